// Round 3
// baseline (285.017 us; speedup 1.0000x reference)
//
#include <hip/hip_runtime.h>

// Problem constants (from reference): B=8, L=4096, D=1024, G=128, d=8
#define PB 8
#define PL 4096
#define PD 1024
#define PG 128
#define SEG 16
#define NSEG (PL / SEG)          // 256
#define NEPS 1e-5f

// d_out layout (flat float32): [y: B*L*D][count: B][mean: B*G][var: B*G]
#define YSZ ((size_t)PB * PL * PD)
#define COUNT_OFF (YSZ)
#define MEAN_OFF (YSZ + PB)
#define VAR_OFF (YSZ + PB + (size_t)PB * PG)

// State per (b,g): n = #elements, S = sum(x), Q = sum(x^2). Merge is pure
// addition -> no divide/shuffle on any loop-carried chain.
// Thread mapping: one thread owns one full group (d=8 -> 2 contiguous
// float4s, 32 B/thread; 128 threads cover one 4 KB timestep row, perfectly
// coalesced). No cross-lane ops anywhere.

// K1: per-(b, seg, g) aggregate over SEG steps. Grid = B*NSEG, 128 thr.
__global__ __launch_bounds__(128) void k_agg(const float* __restrict__ x,
                                             const int* __restrict__ mask,
                                             float* __restrict__ aggN,
                                             float* __restrict__ aggS,
                                             float* __restrict__ aggQ) {
    int blk = blockIdx.x;
    int b = blk >> 8;              // / NSEG (256)
    int seg = blk & (NSEG - 1);
    int g = threadIdx.x;
    size_t row0 = (size_t)b * PL + (size_t)seg * SEG;
    const float4* xp = (const float4*)x + row0 * (PD / 4) + 2 * g;
    const int* mp = mask + b * PL + seg * SEG;

    float nc = 0.f, S = 0.f, Q = 0.f;
#pragma unroll 8
    for (int t = 0; t < SEG; ++t) {
        float4 a = xp[(size_t)t * (PD / 4)];
        float4 c = xp[(size_t)t * (PD / 4) + 1];
        float f = (float)mp[t];
        nc += f;
        float s = (a.x + a.y) + (a.z + a.w) + ((c.x + c.y) + (c.z + c.w));
        float q = fmaf(a.x, a.x, fmaf(a.y, a.y, fmaf(a.z, a.z, fmaf(a.w, a.w,
                  fmaf(c.x, c.x, fmaf(c.y, c.y, fmaf(c.z, c.z, c.w * c.w)))))));
        S = fmaf(f, s, S);
        Q = fmaf(f, q, Q);
    }
    int idx = blk * PG + g;
    aggN[idx] = 8.0f * nc;
    aggS[idx] = S;
    aggQ[idx] = Q;
}

// K2: per-(b,g) exclusive prefix over NSEG aggregates, IN PLACE (carry
// overwrites agg after it is read). Double-buffered tiles of 8 hide load
// latency. Also writes final count/mean/var.
#define TP 8
__global__ __launch_bounds__(128) void k_scan(const void* __restrict__ prev_count,
                                              const float* __restrict__ prev_mean,
                                              const float* __restrict__ prev_var,
                                              float* __restrict__ aggN,
                                              float* __restrict__ aggS,
                                              float* __restrict__ aggQ,
                                              float* __restrict__ out) {
    int tid = blockIdx.x * 128 + threadIdx.x;
    int b = tid >> 7;
    int g = tid & (PG - 1);

    // prev_count is int64 per reference; int32 fallback heuristic.
    const long long* p64 = (const long long*)prev_count;
    const int* p32 = (const int*)prev_count;
    long long pv = p64[b];
    float c = (pv >= 0 && pv < (1LL << 31)) ? (float)pv : (float)p32[b];

    float n = 8.0f * c;
    float m0 = prev_mean[tid];
    float S = m0 * n;
    float Q = fmaf(m0, m0, prev_var[tid]) * n;   // (var + mean^2) * n

    const int base = b * NSEG * PG + g;          // stride PG per segment
    float anA[TP], aSA[TP], aQA[TP], anB[TP], aSB[TP], aQB[TP];

#pragma unroll
    for (int j = 0; j < TP; ++j) {               // preload tile A = [0,8)
        int idx = base + j * PG;
        anA[j] = aggN[idx]; aSA[j] = aggS[idx]; aQA[j] = aggQ[idx];
    }
#pragma unroll 1
    for (int t0 = 0; t0 < NSEG; t0 += 2 * TP) {
#pragma unroll
        for (int j = 0; j < TP; ++j) {           // load tile B = [t0+8, t0+16)
            int idx = base + (t0 + TP + j) * PG;
            anB[j] = aggN[idx]; aSB[j] = aggS[idx]; aQB[j] = aggQ[idx];
        }
#pragma unroll
        for (int j = 0; j < TP; ++j) {           // process A (write carries)
            int idx = base + (t0 + j) * PG;
            aggN[idx] = n; aggS[idx] = S; aggQ[idx] = Q;
            n += anA[j]; S += aSA[j]; Q += aQA[j];
        }
        if (t0 + 2 * TP < NSEG) {
#pragma unroll
            for (int j = 0; j < TP; ++j) {       // load next A = [t0+16, t0+24)
                int idx = base + (t0 + 2 * TP + j) * PG;
                anA[j] = aggN[idx]; aSA[j] = aggS[idx]; aQA[j] = aggQ[idx];
            }
        }
#pragma unroll
        for (int j = 0; j < TP; ++j) {           // process B
            int idx = base + (t0 + TP + j) * PG;
            aggN[idx] = n; aggS[idx] = S; aggQ[idx] = Q;
            n += anB[j]; S += aSB[j]; Q += aQB[j];
        }
    }
    float inv = 1.0f / n;
    float mean = S * inv;
    out[MEAN_OFF + tid] = mean;
    out[VAR_OFF + tid] = fmaf(-mean, mean, Q * inv);
    if (g == 0) out[COUNT_OFF + b] = n * 0.125f;   // exact: n = 8*count
}

// K3: per-(b, seg) ordered walk of SEG steps from the carry. Carried chain
// is 3 FMAs/step; rcp/rsq off-chain; no cross-lane ops.
__global__ __launch_bounds__(128) void k_out(const float* __restrict__ x,
                                             const int* __restrict__ mask,
                                             const float* __restrict__ weight,
                                             const float* __restrict__ bias,
                                             const float* __restrict__ carN,
                                             const float* __restrict__ carS,
                                             const float* __restrict__ carQ,
                                             float* __restrict__ out) {
    int blk = blockIdx.x;
    int b = blk >> 8;
    int seg = blk & (NSEG - 1);
    int g = threadIdx.x;

    int cidx = blk * PG + g;
    float n = carN[cidx];
    float S = carS[cidx];
    float Q = carQ[cidx];

    size_t row0 = (size_t)b * PL + (size_t)seg * SEG;
    const float4* xp = (const float4*)x + row0 * (PD / 4) + 2 * g;
    float4* yp = (float4*)out + row0 * (PD / 4) + 2 * g;
    const int* mp = mask + b * PL + seg * SEG;

    float4 wa = ((const float4*)weight)[2 * g];
    float4 wb = ((const float4*)weight)[2 * g + 1];
    float4 ba = ((const float4*)bias)[2 * g];
    float4 bb = ((const float4*)bias)[2 * g + 1];
    wa.x += 1.0f; wa.y += 1.0f; wa.z += 1.0f; wa.w += 1.0f;
    wb.x += 1.0f; wb.y += 1.0f; wb.z += 1.0f; wb.w += 1.0f;

    float4 va = xp[0];
    float4 vb = xp[1];
#pragma unroll
    for (int t = 0; t < SEG; ++t) {
        int tn = (t + 1 < SEG) ? (t + 1) : t;
        float4 na = xp[(size_t)tn * (PD / 4)];
        float4 nb = xp[(size_t)tn * (PD / 4) + 1];
        float f = (float)mp[t];
        float s = (va.x + va.y) + (va.z + va.w) + ((vb.x + vb.y) + (vb.z + vb.w));
        float q = fmaf(va.x, va.x, fmaf(va.y, va.y, fmaf(va.z, va.z, fmaf(va.w, va.w,
                  fmaf(vb.x, vb.x, fmaf(vb.y, vb.y, fmaf(vb.z, vb.z, vb.w * vb.w)))))));
        n = fmaf(f, 8.0f, n);
        S = fmaf(f, s, S);
        Q = fmaf(f, q, Q);
        float inv  = __builtin_amdgcn_rcpf(n);
        float mean = S * inv;
        float var  = fmaf(-mean, mean, Q * inv);
        float rstd = __builtin_amdgcn_rsqf(var + NEPS);
        float4 ya, yb;
        ya.x = fmaf((va.x - mean) * rstd, wa.x, ba.x);
        ya.y = fmaf((va.y - mean) * rstd, wa.y, ba.y);
        ya.z = fmaf((va.z - mean) * rstd, wa.z, ba.z);
        ya.w = fmaf((va.w - mean) * rstd, wa.w, ba.w);
        yb.x = fmaf((vb.x - mean) * rstd, wb.x, bb.x);
        yb.y = fmaf((vb.y - mean) * rstd, wb.y, bb.y);
        yb.z = fmaf((vb.z - mean) * rstd, wb.z, bb.z);
        yb.w = fmaf((vb.w - mean) * rstd, wb.w, bb.w);
        yp[(size_t)t * (PD / 4)] = ya;
        yp[(size_t)t * (PD / 4) + 1] = yb;
        va = na; vb = nb;
    }
}

extern "C" void kernel_launch(void* const* d_in, const int* in_sizes, int n_in,
                              void* d_out, int out_size, void* d_ws, size_t ws_size,
                              hipStream_t stream) {
    const float* x          = (const float*)d_in[0];
    const void*  prev_count = d_in[1];
    const float* prev_mean  = (const float*)d_in[2];
    const float* prev_var   = (const float*)d_in[3];
    const float* weight     = (const float*)d_in[4];
    const float* bias       = (const float*)d_in[5];
    const int*   mask       = (const int*)d_in[6];
    float* out = (float*)d_out;
    float* ws  = (float*)d_ws;

    const size_t A = (size_t)PB * NSEG * PG;   // 262144 floats per array
    float* aggN = ws + 0 * A;
    float* aggS = ws + 1 * A;
    float* aggQ = ws + 2 * A;                  // 3 MiB total; scanned in place

    hipLaunchKernelGGL(k_agg, dim3(PB * NSEG), dim3(128), 0, stream,
                       x, mask, aggN, aggS, aggQ);
    hipLaunchKernelGGL(k_scan, dim3(PB * PG / 128), dim3(128), 0, stream,
                       prev_count, prev_mean, prev_var,
                       aggN, aggS, aggQ, out);
    hipLaunchKernelGGL(k_out, dim3(PB * NSEG), dim3(128), 0, stream,
                       x, mask, weight, bias, aggN, aggS, aggQ, out);
}